// Round 8
// baseline (54.562 us; speedup 1.0000x reference)
//
#include <hip/hip_runtime.h>
#include <hip/hip_bf16.h>
#include <stdint.h>
#include <math.h>

#define RES     256
#define M_MEAS  8192
#define KDIM    8192
#define ROWSC   2048        // 4 batches * {Re 0..255, Im 256..511}
#define NCOLS   288         // cos u at [0,129)+pad, sin u at [144,273)+pad
#define SINOFF  144
#define SPLIT   16
#define KCHUNK  512
#define BM      128
#define BN      144
#define BK      64
#define NT      (KCHUNK / BK)   // 8
#define TWO_PI  6.28318530717958647692f

typedef __attribute__((ext_vector_type(8))) __bf16 bf16x8;
typedef __attribute__((ext_vector_type(8))) unsigned short u16x8;
typedef __attribute__((ext_vector_type(4))) float f32x4;
typedef __attribute__((ext_vector_type(2))) float f32x2;

// ---- workspace layout (bytes) ----
#define OFF_SRE 0
#define OFF_SIM 131072
#define OFF_KY  262144
#define OFF_B   294912
#define OFF_C   5013504

__device__ __forceinline__ unsigned short f2bf(float f) {
    unsigned u = __float_as_uint(f);
    u += 0x7FFFu + ((u >> 16) & 1u);          // round-to-nearest-even
    return (unsigned short)(u >> 16);
}

__device__ __forceinline__ float bf2f(unsigned short v) {
    unsigned u = ((unsigned)v) << 16;
    return __uint_as_float(u);
}

__device__ __forceinline__ void lds_load16(const void* g, void* l) {
    __builtin_amdgcn_global_load_lds(
        (const __attribute__((address_space(1))) uint32_t*)(uintptr_t)g,
        (__attribute__((address_space(3))) uint32_t*)(uint32_t)(uintptr_t)l,
        16, 0, 0);
}

// ---------------- kernel 1: gather s + ky + incremental-rotation Bt ------------------
__global__ __launch_bounds__(256) void k_prep(const float* __restrict__ in,
                                              const float* __restrict__ xs,
                                              float* __restrict__ sRe,
                                              float* __restrict__ sIm,
                                              float* __restrict__ kyc,
                                              unsigned short* __restrict__ Bt) {
    int t = blockIdx.x * 256 + threadIdx.x;
    if (t < 32768) {
        // ---- bilinear gather of complex k-space samples ----
        int b = t >> 13, m = t & (M_MEAS - 1);
        float kx = xs[2 * m + 0], ky = xs[2 * m + 1];
        if (t < M_MEAS) kyc[t] = xs[2 * t + 1];
        float gx = (kx * (1.0f / 128.0f) + 1.0f) * 0.5f * 255.0f;
        float gy = (ky * (1.0f / 128.0f) + 1.0f) * 0.5f * 255.0f;
        float fx0 = floorf(gx), fy0 = floorf(gy);
        float wx1 = gx - fx0, wx0 = 1.0f - wx1;
        float wy1 = gy - fy0, wy0 = 1.0f - wy1;
        int x0 = (int)fx0, y0 = (int)fy0;
        float re = 0.0f, im = 0.0f;
#pragma unroll
        for (int dy = 0; dy < 2; ++dy) {
#pragma unroll
            for (int dx = 0; dx < 2; ++dx) {
                int xi = x0 + dx, yi = y0 + dy;
                bool v = (xi >= 0) && (xi < RES) && (yi >= 0) && (yi < RES);
                int xc = min(max(xi, 0), RES - 1);
                int yc = min(max(yi, 0), RES - 1);
                float w = (dx ? wx1 : wx0) * (dy ? wy1 : wy0) * (v ? 1.0f : 0.0f);
                const float* p = in + ((((size_t)b * RES + yc) * RES + xc) * 2);
                re += p[0] * w;
                im += p[1] * w;
            }
        }
        sRe[b * M_MEAS + m] = re;
        sIm[b * M_MEAS + m] = im;
    } else if (t < 50176) {
        // ---- Bt rows via incremental rotation: 1 sincos-pair per (m, u-block) ----
        int z = t - 32768;                         // 0..17407
        int ub = z >> 10, mb = z & 1023;           // ub 0..16 (16 => u=128 only)
        int m0 = mb * 8, u0 = ub * 8;
        int nr = (ub == 16) ? 1 : 8;
        u16x8 vc[8], vs[8];
#pragma unroll
        for (int j = 0; j < 8; ++j) {
            float kx = xs[2 * (m0 + j) + 0];
            float a0 = kx * (float)u0 * (1.0f / 256.0f); a0 -= rintf(a0);
            float c = __cosf(a0 * TWO_PI), s = __sinf(a0 * TWO_PI);
            float st = kx * (1.0f / 256.0f); st -= rintf(st);
            float cs = __cosf(st * TWO_PI), ss = __sinf(st * TWO_PI);
#pragma unroll
            for (int r = 0; r < 8; ++r) {
                vc[r][j] = f2bf(c); vs[r][j] = f2bf(s);
                float nc = fmaf(c, cs, -(s * ss));
                float ns = fmaf(s, cs, (c * ss));
                c = nc; s = ns;
            }
        }
#pragma unroll
        for (int r = 0; r < 8; ++r) {
            if (r < nr) {
                *(u16x8*)(Bt + (size_t)(u0 + r) * KDIM + m0)          = vc[r];
                *(u16x8*)(Bt + (size_t)(SINOFF + u0 + r) * KDIM + m0) = vs[r];
            }
        }
    } else {
        // ---- zero pad rows 129..143 and 273..287 ----
        int z = t - 50176;                         // 0..30719
        int rr = z >> 10, mb8 = (z & 1023) * 8;
        int row = (rr < 15) ? (129 + rr) : (273 + rr - 15);
        *(u16x8*)(Bt + (size_t)row * KDIM + mb8) = (u16x8){0, 0, 0, 0, 0, 0, 0, 0};
    }
}

// ---------------- kernel 2: split-K GEMM, on-the-fly A (identical to round 6) --------
__global__ __launch_bounds__(256, 2) void k_gemm(const float* __restrict__ sReG,
                                                 const float* __restrict__ sImG,
                                                 const float* __restrict__ kyG,
                                                 const unsigned short* __restrict__ Bt,
                                                 unsigned short* __restrict__ Cp) {
    __shared__ __align__(16) unsigned short As[2][BM * BK];   // 2 x 16 KB
    __shared__ __align__(16) unsigned short Bs[2][BN * BK];   // 2 x 18 KB
    __shared__ __align__(16) float sbuf[3 * KCHUNK];          // 6 KB

    int bid = blockIdx.x;              // 512 = 2 col * 16 row * 16 split
    int tc = bid & 1, rest = bid >> 1;
    int tr = rest & 15, split = rest >> 4;
    int col0 = tc * BN;
    int kbase = split * KCHUNK;
    int yhalf = tr & 1, isIm = (tr >> 1) & 1, batch = tr >> 2;
    int tid = threadIdx.x;
    int w = tid >> 6, l = tid & 63;
    int lr = l & 15, lu = l >> 4;

    f32x4 acc[2][9] = {};

#define STAGE_B(buf, kt)                                                          \
    do {                                                                          \
        _Pragma("unroll")                                                         \
        for (int q = 0; q < 5; ++q) {                                             \
            int U = q * 256 + tid; if (U >= 1152) U -= 1152;                      \
            int r = U >> 3, u = U & 7;                                            \
            lds_load16(Bt + (size_t)(col0 + r) * KDIM + kbase + (kt) * BK         \
                          + ((u ^ (r & 7)) * 8),                                  \
                       &Bs[buf][U * 8]);                                          \
        }                                                                         \
    } while (0)

#define GEN_A(buf, kt)                                                            \
    do {                                                                          \
        int p = tid & 31, g = tid >> 5;                                           \
        int mi = (kt) * BK + p * 2;                                               \
        float2 kyp = *(const float2*)&sbuf[mi];                                   \
        float2 srp = *(const float2*)&sbuf[KCHUNK + mi];                          \
        float2 sip = *(const float2*)&sbuf[2 * KCHUNK + mi];                      \
        float n0 = (float)(yhalf * 128 + g * 16 - 128);                           \
        float c0, s0, c1, s1, cs0, ss0, cs1, ss1;                                 \
        { float u = kyp.x * n0 * (1.0f/256.0f); u -= rintf(u);                    \
          s0 = __sinf(u * TWO_PI); c0 = __cosf(u * TWO_PI); }                     \
        { float u = kyp.x * (1.0f/256.0f); u -= rintf(u);                         \
          ss0 = __sinf(u * TWO_PI); cs0 = __cosf(u * TWO_PI); }                   \
        { float u = kyp.y * n0 * (1.0f/256.0f); u -= rintf(u);                    \
          s1 = __sinf(u * TWO_PI); c1 = __cosf(u * TWO_PI); }                     \
        { float u = kyp.y * (1.0f/256.0f); u -= rintf(u);                         \
          ss1 = __sinf(u * TWO_PI); cs1 = __cosf(u * TWO_PI); }                   \
        _Pragma("unroll")                                                         \
        for (int j = 0; j < 16; ++j) {                                            \
            int r = g * 16 + j;                                                   \
            float v0 = isIm ? fmaf(srp.x, s0, sip.x * c0)                         \
                            : fmaf(srp.x, c0, -(sip.x * s0));                     \
            float v1 = isIm ? fmaf(srp.y, s1, sip.y * c1)                         \
                            : fmaf(srp.y, c1, -(sip.y * s1));                     \
            unsigned pk = (unsigned)f2bf(v0) | ((unsigned)f2bf(v1) << 16);        \
            *(unsigned*)&As[buf][r * 64 + (((p >> 2) ^ (r & 7)) * 8) + (p & 3) * 2] = pk; \
            float nc0 = fmaf(c0, cs0, -(s0 * ss0));                               \
            float ns0 = fmaf(s0, cs0,  (c0 * ss0));                               \
            c0 = nc0; s0 = ns0;                                                   \
            float nc1 = fmaf(c1, cs1, -(s1 * ss1));                               \
            float ns1 = fmaf(s1, cs1,  (c1 * ss1));                               \
            c1 = nc1; s1 = ns1;                                                   \
        }                                                                         \
    } while (0)

#pragma unroll
    for (int q = 0; q < 2; ++q) {
        int V = q * 256 + tid; if (V >= 384) V -= 384;
        int rg = V >> 7, idx = V & 127;
        const float* s = (rg == 0) ? kyG
                       : (rg == 1) ? (sReG + (size_t)batch * M_MEAS)
                                   : (sImG + (size_t)batch * M_MEAS);
        lds_load16(s + kbase + idx * 4, &sbuf[V * 4]);
    }
    STAGE_B(0, 0);
    asm volatile("s_waitcnt vmcnt(5)" ::: "memory");
    __builtin_amdgcn_s_barrier();
    GEN_A(0, 0);
    asm volatile("s_waitcnt vmcnt(0) lgkmcnt(0)" ::: "memory");
    __builtin_amdgcn_sched_barrier(0);
    __builtin_amdgcn_s_barrier();

    for (int t = 0; t < NT; ++t) {
        int cur = t & 1;
        if (t < NT - 1) {
            STAGE_B(cur ^ 1, t + 1);
            GEN_A(cur ^ 1, t + 1);
        }

        bf16x8 af[2][2], bfr[2][9];
#pragma unroll
        for (int ks = 0; ks < 2; ++ks) {
            int uu = ks * 4 + lu;
#pragma unroll
            for (int i = 0; i < 2; ++i) {
                int r = w * 32 + i * 16 + lr;
                af[ks][i] = *(const bf16x8*)&As[cur][r * 64 + ((uu ^ (r & 7)) * 8)];
            }
#pragma unroll
            for (int j = 0; j < 9; ++j) {
                int r = j * 16 + lr;
                bfr[ks][j] = *(const bf16x8*)&Bs[cur][r * 64 + ((uu ^ (r & 7)) * 8)];
            }
        }
        asm volatile("s_waitcnt lgkmcnt(0)" ::: "memory");
        __builtin_amdgcn_sched_barrier(0);
        __builtin_amdgcn_s_setprio(1);
#pragma unroll
        for (int ks = 0; ks < 2; ++ks)
#pragma unroll
            for (int i = 0; i < 2; ++i)
#pragma unroll
                for (int j = 0; j < 9; ++j)
                    acc[i][j] = __builtin_amdgcn_mfma_f32_16x16x32_bf16(af[ks][i], bfr[ks][j], acc[i][j], 0, 0, 0);
        __builtin_amdgcn_s_setprio(0);
        asm volatile("s_waitcnt vmcnt(0)" ::: "memory");
        __builtin_amdgcn_sched_barrier(0);
        __builtin_amdgcn_s_barrier();
    }
#undef STAGE_B
#undef GEN_A

    unsigned short* Cb = Cp + (size_t)split * ROWSC * NCOLS;
#pragma unroll
    for (int i = 0; i < 2; ++i) {
#pragma unroll
        for (int j = 0; j < 9; ++j) {
            int colg = col0 + j * 16 + lr;
#pragma unroll
            for (int v = 0; v < 4; ++v) {
                int rowg = tr * BM + w * 32 + i * 16 + lu * 4 + v;
                Cb[(size_t)rowg * NCOLS + colg] = f2bf(acc[i][j][v]);
            }
        }
    }
}

// ---------------- kernel 3: split-K reduce; one read -> both +/- x outputs -----------
__global__ __launch_bounds__(256) void k_combine(const unsigned short* __restrict__ Cp,
                                                 float* __restrict__ out) {
    int t = blockIdx.x * 256 + threadIdx.x;       // 17408 = 17 ub * 4b * 256y
    int ub = t >> 10;                             // 0..16
    int rest2 = t & 1023;
    int b = rest2 >> 8, y = rest2 & 255;
    int u0 = ub * 8;
    size_t rRe = ((size_t)b * 512 + y) * NCOLS;
    size_t rIm = rRe + (size_t)256 * NCOLS;
    float cr[8] = {}, sr8[8] = {}, ci8[8] = {}, si8[8] = {};
#pragma unroll
    for (int s2 = 0; s2 < SPLIT; ++s2) {
        const unsigned short* Cb = Cp + (size_t)s2 * ROWSC * NCOLS;
        u16x8 va = *(const u16x8*)(Cb + rRe + u0);            // cos * Re_t
        u16x8 vb = *(const u16x8*)(Cb + rRe + SINOFF + u0);   // sin * Re_t
        u16x8 vc = *(const u16x8*)(Cb + rIm + u0);            // cos * Im_t
        u16x8 vd = *(const u16x8*)(Cb + rIm + SINOFF + u0);   // sin * Im_t
#pragma unroll
        for (int k = 0; k < 8; ++k) {
            cr[k]  += bf2f(va[k]);
            sr8[k] += bf2f(vb[k]);
            ci8[k] += bf2f(vc[k]);
            si8[k] += bf2f(vd[k]);
        }
    }
    float* ob = out + (size_t)(b * 256 + y) * 512;            // row of 256 (re,im) pairs
#pragma unroll
    for (int k = 0; k < 8; ++k) {
        int u = u0 + k;
        if (u <= 127) {                                        // pos: x = 128+u
            ((f32x2*)ob)[128 + u] = (f32x2){cr[k] - si8[k], sr8[k] + ci8[k]};
        }
        if (u >= 1 && u <= 128) {                              // neg: x = 128-u
            ((f32x2*)ob)[128 - u] = (f32x2){cr[k] + si8[k], ci8[k] - sr8[k]};
        }
    }
}

extern "C" void kernel_launch(void* const* d_in, const int* in_sizes, int n_in,
                              void* d_out, int out_size, void* d_ws, size_t ws_size,
                              hipStream_t stream) {
    const float* in = (const float*)d_in[0];
    const float* xs = (const float*)d_in[1];
    float* out = (float*)d_out;
    char* ws = (char*)d_ws;

    float* sRe = (float*)(ws + OFF_SRE);
    float* sIm = (float*)(ws + OFF_SIM);
    float* kyc = (float*)(ws + OFF_KY);
    unsigned short* Bt = (unsigned short*)(ws + OFF_B);
    unsigned short* Cp = (unsigned short*)(ws + OFF_C);

    k_prep   <<<316, 256, 0, stream>>>(in, xs, sRe, sIm, kyc, Bt);
    k_gemm   <<<512, 256, 0, stream>>>(sRe, sIm, kyc, Bt, Cp);
    k_combine<<<68,  256, 0, stream>>>(Cp, out);
}

// Round 9
// 40.588 us; speedup vs baseline: 1.3443x; 1.3443x over previous
//
#include <hip/hip_runtime.h>
#include <hip/hip_bf16.h>
#include <stdint.h>
#include <math.h>

#define RES     256
#define M_MEAS  8192
#define KDIM    8192
#define ROWSC   2048        // 4 batches * {Re 0..255, Im 256..511}
#define NCOLS   288         // cos u at [0,129)+pad, sin u at [144,273)+pad
#define SINOFF  144
#define SPLIT   16
#define KCHUNK  512
#define BM      128
#define BN      144
#define BK      64
#define NT      (KCHUNK / BK)   // 8
#define TWO_PI  6.28318530717958647692f

typedef __attribute__((ext_vector_type(8))) __bf16 bf16x8;
typedef __attribute__((ext_vector_type(8))) unsigned short u16x8;
typedef __attribute__((ext_vector_type(4))) float f32x4;
typedef __attribute__((ext_vector_type(2))) float f32x2;

// ---- workspace layout (bytes) ----
#define OFF_SRE 0
#define OFF_SIM 131072
#define OFF_KY  262144
#define OFF_B   294912
#define OFF_C   5013504

__device__ __forceinline__ unsigned short f2bf(float f) {
    unsigned u = __float_as_uint(f);
    u += 0x7FFFu + ((u >> 16) & 1u);          // round-to-nearest-even
    return (unsigned short)(u >> 16);
}

__device__ __forceinline__ float bf2f(unsigned short v) {
    unsigned u = ((unsigned)v) << 16;
    return __uint_as_float(u);
}

__device__ __forceinline__ void lds_load16(const void* g, void* l) {
    __builtin_amdgcn_global_load_lds(
        (const __attribute__((address_space(1))) uint32_t*)(uintptr_t)g,
        (__attribute__((address_space(3))) uint32_t*)(uint32_t)(uintptr_t)l,
        16, 0, 0);
}

// ---------------- kernel 1: gather s + ky + build deduped Bt (round-6 exact) ---------
__global__ __launch_bounds__(256) void k_prep(const float* __restrict__ in,
                                              const float* __restrict__ xs,
                                              float* __restrict__ sRe,
                                              float* __restrict__ sIm,
                                              float* __restrict__ kyc,
                                              unsigned short* __restrict__ Bt) {
    int blk = blockIdx.x;
    if (blk < 128) {
        int t = blk * 256 + threadIdx.x;          // 32768
        int b = t >> 13, m = t & (M_MEAS - 1);
        float kx = xs[2 * m + 0], ky = xs[2 * m + 1];
        if (t < M_MEAS) kyc[t] = xs[2 * t + 1];
        float gx = (kx * (1.0f / 128.0f) + 1.0f) * 0.5f * 255.0f;
        float gy = (ky * (1.0f / 128.0f) + 1.0f) * 0.5f * 255.0f;
        float fx0 = floorf(gx), fy0 = floorf(gy);
        float wx1 = gx - fx0, wx0 = 1.0f - wx1;
        float wy1 = gy - fy0, wy0 = 1.0f - wy1;
        int x0 = (int)fx0, y0 = (int)fy0;
        float re = 0.0f, im = 0.0f;
#pragma unroll
        for (int dy = 0; dy < 2; ++dy) {
#pragma unroll
            for (int dx = 0; dx < 2; ++dx) {
                int xi = x0 + dx, yi = y0 + dy;
                bool v = (xi >= 0) && (xi < RES) && (yi >= 0) && (yi < RES);
                int xc = min(max(xi, 0), RES - 1);
                int yc = min(max(yi, 0), RES - 1);
                float w = (dx ? wx1 : wx0) * (dy ? wy1 : wy0) * (v ? 1.0f : 0.0f);
                const float* p = in + ((((size_t)b * RES + yc) * RES + xc) * 2);
                re += p[0] * w;
                im += p[1] * w;
            }
        }
        sRe[b * M_MEAS + m] = re;
        sIm[b * M_MEAS + m] = im;
    } else {
        int t = (blk - 128) * 256 + threadIdx.x;  // 294912 = 288*1024
        int cidx = t >> 10;
        int m0 = (t & 1023) * 8;
        bool isCos = cidx < SINOFF;
        int u = isCos ? cidx : (cidx - SINOFF);
        u16x8 v;
        if (u > 128) {
            v = (u16x8){0, 0, 0, 0, 0, 0, 0, 0};
        } else {
            float nn = (float)u;
#pragma unroll
            for (int j = 0; j < 8; ++j) {
                float kx = xs[2 * (m0 + j) + 0];
                float ur = kx * nn * (1.0f / 256.0f);
                ur -= rintf(ur);
                float th = ur * TWO_PI;
                v[j] = f2bf(isCos ? __cosf(th) : __sinf(th));
            }
        }
        *(u16x8*)(Bt + (size_t)cidx * KDIM + m0) = v;
    }
}

// ---------------- kernel 2: split-K GEMM, on-the-fly A (round-6 exact) ---------------
__global__ __launch_bounds__(256, 2) void k_gemm(const float* __restrict__ sReG,
                                                 const float* __restrict__ sImG,
                                                 const float* __restrict__ kyG,
                                                 const unsigned short* __restrict__ Bt,
                                                 unsigned short* __restrict__ Cp) {
    __shared__ __align__(16) unsigned short As[2][BM * BK];   // 2 x 16 KB
    __shared__ __align__(16) unsigned short Bs[2][BN * BK];   // 2 x 18 KB
    __shared__ __align__(16) float sbuf[3 * KCHUNK];          // 6 KB

    int bid = blockIdx.x;              // 512 = 2 col * 16 row * 16 split
    int tc = bid & 1, rest = bid >> 1;
    int tr = rest & 15, split = rest >> 4;
    int col0 = tc * BN;
    int kbase = split * KCHUNK;
    int yhalf = tr & 1, isIm = (tr >> 1) & 1, batch = tr >> 2;
    int tid = threadIdx.x;
    int w = tid >> 6, l = tid & 63;
    int lr = l & 15, lu = l >> 4;

    f32x4 acc[2][9] = {};

#define STAGE_B(buf, kt)                                                          \
    do {                                                                          \
        _Pragma("unroll")                                                         \
        for (int q = 0; q < 5; ++q) {                                             \
            int U = q * 256 + tid; if (U >= 1152) U -= 1152;                      \
            int r = U >> 3, u = U & 7;                                            \
            lds_load16(Bt + (size_t)(col0 + r) * KDIM + kbase + (kt) * BK         \
                          + ((u ^ (r & 7)) * 8),                                  \
                       &Bs[buf][U * 8]);                                          \
        }                                                                         \
    } while (0)

#define GEN_A(buf, kt)                                                            \
    do {                                                                          \
        int p = tid & 31, g = tid >> 5;                                           \
        int mi = (kt) * BK + p * 2;                                               \
        float2 kyp = *(const float2*)&sbuf[mi];                                   \
        float2 srp = *(const float2*)&sbuf[KCHUNK + mi];                          \
        float2 sip = *(const float2*)&sbuf[2 * KCHUNK + mi];                      \
        float n0 = (float)(yhalf * 128 + g * 16 - 128);                           \
        float c0, s0, c1, s1, cs0, ss0, cs1, ss1;                                 \
        { float u = kyp.x * n0 * (1.0f/256.0f); u -= rintf(u);                    \
          s0 = __sinf(u * TWO_PI); c0 = __cosf(u * TWO_PI); }                     \
        { float u = kyp.x * (1.0f/256.0f); u -= rintf(u);                         \
          ss0 = __sinf(u * TWO_PI); cs0 = __cosf(u * TWO_PI); }                   \
        { float u = kyp.y * n0 * (1.0f/256.0f); u -= rintf(u);                    \
          s1 = __sinf(u * TWO_PI); c1 = __cosf(u * TWO_PI); }                     \
        { float u = kyp.y * (1.0f/256.0f); u -= rintf(u);                         \
          ss1 = __sinf(u * TWO_PI); cs1 = __cosf(u * TWO_PI); }                   \
        _Pragma("unroll")                                                         \
        for (int j = 0; j < 16; ++j) {                                            \
            int r = g * 16 + j;                                                   \
            float v0 = isIm ? fmaf(srp.x, s0, sip.x * c0)                         \
                            : fmaf(srp.x, c0, -(sip.x * s0));                     \
            float v1 = isIm ? fmaf(srp.y, s1, sip.y * c1)                         \
                            : fmaf(srp.y, c1, -(sip.y * s1));                     \
            unsigned pk = (unsigned)f2bf(v0) | ((unsigned)f2bf(v1) << 16);        \
            *(unsigned*)&As[buf][r * 64 + (((p >> 2) ^ (r & 7)) * 8) + (p & 3) * 2] = pk; \
            float nc0 = fmaf(c0, cs0, -(s0 * ss0));                               \
            float ns0 = fmaf(s0, cs0,  (c0 * ss0));                               \
            c0 = nc0; s0 = ns0;                                                   \
            float nc1 = fmaf(c1, cs1, -(s1 * ss1));                               \
            float ns1 = fmaf(s1, cs1,  (c1 * ss1));                               \
            c1 = nc1; s1 = ns1;                                                   \
        }                                                                         \
    } while (0)

#pragma unroll
    for (int q = 0; q < 2; ++q) {
        int V = q * 256 + tid; if (V >= 384) V -= 384;
        int rg = V >> 7, idx = V & 127;
        const float* s = (rg == 0) ? kyG
                       : (rg == 1) ? (sReG + (size_t)batch * M_MEAS)
                                   : (sImG + (size_t)batch * M_MEAS);
        lds_load16(s + kbase + idx * 4, &sbuf[V * 4]);
    }
    STAGE_B(0, 0);
    asm volatile("s_waitcnt vmcnt(5)" ::: "memory");
    __builtin_amdgcn_s_barrier();
    GEN_A(0, 0);
    asm volatile("s_waitcnt vmcnt(0) lgkmcnt(0)" ::: "memory");
    __builtin_amdgcn_sched_barrier(0);
    __builtin_amdgcn_s_barrier();

    for (int t = 0; t < NT; ++t) {
        int cur = t & 1;
        if (t < NT - 1) {
            STAGE_B(cur ^ 1, t + 1);
            GEN_A(cur ^ 1, t + 1);
        }

        bf16x8 af[2][2], bfr[2][9];
#pragma unroll
        for (int ks = 0; ks < 2; ++ks) {
            int uu = ks * 4 + lu;
#pragma unroll
            for (int i = 0; i < 2; ++i) {
                int r = w * 32 + i * 16 + lr;
                af[ks][i] = *(const bf16x8*)&As[cur][r * 64 + ((uu ^ (r & 7)) * 8)];
            }
#pragma unroll
            for (int j = 0; j < 9; ++j) {
                int r = j * 16 + lr;
                bfr[ks][j] = *(const bf16x8*)&Bs[cur][r * 64 + ((uu ^ (r & 7)) * 8)];
            }
        }
        asm volatile("s_waitcnt lgkmcnt(0)" ::: "memory");
        __builtin_amdgcn_sched_barrier(0);
        __builtin_amdgcn_s_setprio(1);
#pragma unroll
        for (int ks = 0; ks < 2; ++ks)
#pragma unroll
            for (int i = 0; i < 2; ++i)
#pragma unroll
                for (int j = 0; j < 9; ++j)
                    acc[i][j] = __builtin_amdgcn_mfma_f32_16x16x32_bf16(af[ks][i], bfr[ks][j], acc[i][j], 0, 0, 0);
        __builtin_amdgcn_s_setprio(0);
        asm volatile("s_waitcnt vmcnt(0)" ::: "memory");
        __builtin_amdgcn_sched_barrier(0);
        __builtin_amdgcn_s_barrier();
    }
#undef STAGE_B
#undef GEN_A

    unsigned short* Cb = Cp + (size_t)split * ROWSC * NCOLS;
#pragma unroll
    for (int i = 0; i < 2; ++i) {
#pragma unroll
        for (int j = 0; j < 9; ++j) {
            int colg = col0 + j * 16 + lr;
#pragma unroll
            for (int v = 0; v < 4; ++v) {
                int rowg = tr * BM + w * 32 + i * 16 + lu * 4 + v;
                Cb[(size_t)rowg * NCOLS + colg] = f2bf(acc[i][j][v]);
            }
        }
    }
}

// ---------------- kernel 3: block-per-(b,y) cooperative split-K reduce ---------------
// 1024 blocks. 4 waves each own a split-quarter; 16B coalesced loads; LDS tree-reduce
// (9-float padded stride, conflict-free); coalesced f32x2 stores.
__global__ __launch_bounds__(256) void k_combine(const unsigned short* __restrict__ Cp,
                                                 float* __restrict__ out) {
    __shared__ float part[4 * 68 * 9];            // 9792 B
    int blk = blockIdx.x;
    int b = blk >> 8, y = blk & 255;
    int tid = threadIdx.x;
    int q = tid >> 6, un = tid & 63;

    size_t rRe = ((size_t)b * 512 + y) * NCOLS;
    size_t rIm = rRe + (size_t)256 * NCOLS;

    // units: seg 0..3 = {cos*Re, sin*Re, cos*Im, sin*Im}, 17 u16x8 each (68 total)
#pragma unroll
    for (int rep = 0; rep < 2; ++rep) {
        int unit = un + rep * 64;
        if (rep == 1 && un >= 4) break;
        int seg = unit / 17, uidx = unit - seg * 17;
        size_t base = ((seg & 2) ? rIm : rRe) + ((seg & 1) ? SINOFF : 0) + uidx * 8;
        float a[8] = {};
#pragma unroll
        for (int s2 = 0; s2 < 4; ++s2) {
            const unsigned short* Cb = Cp + (size_t)(q * 4 + s2) * ROWSC * NCOLS;
            u16x8 v = *(const u16x8*)(Cb + base);
#pragma unroll
            for (int k = 0; k < 8; ++k) a[k] += bf2f(v[k]);
        }
#pragma unroll
        for (int k = 0; k < 8; ++k) part[(q * 68 + unit) * 9 + k] = a[k];
    }
    __syncthreads();

    if (tid < 68) {
#pragma unroll
        for (int k = 0; k < 8; ++k) {
            float s = part[(0 * 68 + tid) * 9 + k] + part[(1 * 68 + tid) * 9 + k]
                    + part[(2 * 68 + tid) * 9 + k] + part[(3 * 68 + tid) * 9 + k];
            part[tid * 9 + k] = s;                 // final into quarter-0 slots
        }
    }
    __syncthreads();

    int x = tid;
    int n = x - 128;
    int u = (n < 0) ? -n : n;                      // 0..128
    float sg = (n < 0) ? -1.0f : 1.0f;
    int ui = u >> 3, uk = u & 7;
    float cr = part[(0 * 17 + ui) * 9 + uk];
    float sr = part[(17 + ui) * 9 + uk];
    float ci = part[(34 + ui) * 9 + uk];
    float si = part[(51 + ui) * 9 + uk];
    float re = cr - sg * si;
    float im = sg * sr + ci;
    ((f32x2*)out)[(size_t)(b * 256 + y) * 256 + x] = (f32x2){re, im};
}

extern "C" void kernel_launch(void* const* d_in, const int* in_sizes, int n_in,
                              void* d_out, int out_size, void* d_ws, size_t ws_size,
                              hipStream_t stream) {
    const float* in = (const float*)d_in[0];
    const float* xs = (const float*)d_in[1];
    float* out = (float*)d_out;
    char* ws = (char*)d_ws;

    float* sRe = (float*)(ws + OFF_SRE);
    float* sIm = (float*)(ws + OFF_SIM);
    float* kyc = (float*)(ws + OFF_KY);
    unsigned short* Bt = (unsigned short*)(ws + OFF_B);
    unsigned short* Cp = (unsigned short*)(ws + OFF_C);

    k_prep   <<<128 + 1152, 256, 0, stream>>>(in, xs, sRe, sIm, kyc, Bt);
    k_gemm   <<<512,        256, 0, stream>>>(sRe, sIm, kyc, Bt, Cp);
    k_combine<<<1024,       256, 0, stream>>>(Cp, out);
}